// Round 8
// baseline (116.059 us; speedup 1.0000x reference)
//
#include <hip/hip_runtime.h>
#include <hip/hip_bf16.h>

// PartiallyExchangeableNetwork on MI355X (gfx950)
// N=256, M=3, T=4096, ORDER=2 -> L=4094 windows, H=128, OUT=10
//
// h1 = relu(xin @ W1 + b1); h2 = relu(h1 @ W2 + b2); colsum over L.
// Layer 3 folded through the sum: sum_l(h2@W3+b3) = (sum_l h2)@W3 + L*b3 (tail).
//
// R8: LDS-free inner pipeline (R7's permuted-channel trick) + register diet.
// Each of the 4 waves owns 32 outputs (w2f = 32 VGPR) and processes ALL 16-row
// units (L1 duplicated 4x -- MFMA floor ~8us, cheap). Everything fits <128
// unified regs -> 4 waves/SIMD resident AND no AGPR accvgpr-move tax (the
// hidden 44us VALU cost in R7). L1/pack/L2 interleaved per K-chunk so only
// one acc1 pair is live at a time.

#define NN 256
#define MM 3
#define TT 4096
#define LL 4094
#define HH 128
#define CHUNKS 4           // 1024 rows per block; grid = 1024 = 4 blocks/CU
#define STAGES 4           // 4 stages of 256 rows
#define RPS 256            // rows per stage
#define XROW 24            // xw row stride in halfwords (48B, 2-way-free b128)

#define WS_W1 (512 * 1024)             // after 512KB partials
#define WS_W2 (512 * 1024 + 8192)      // w1 table = 512 frags * 16B

typedef __attribute__((ext_vector_type(8))) short bf16x8;
typedef __attribute__((ext_vector_type(4))) float f32x4;
typedef __attribute__((ext_vector_type(4))) unsigned short u16x4;
typedef __attribute__((ext_vector_type(4))) unsigned int u32x4;

__device__ __forceinline__ unsigned short f2bf(float x) {
    __hip_bfloat16 h = __float2bfloat16(x);           // RNE, hw cvt on gfx950
    union { __hip_bfloat16 h; unsigned short u; } v; v.h = h;
    return v.u;
}

// ---------------------------------------------------------------------------
// Prep: fragment tables in d_ws.
// w1t[cf][lane][e]: A-frag, row lr -> channel chan(cf,lr) (permuted so the
//   L1 D-frag pair (2kk,2kk+1) is the L2 B-frag of K-chunk kk), k=8lq+e
//   (k<9: W1; k==9: b1; else 0).
// w2t[w][of][kk][lane][e]: A-frag, o = 32w+16of+lr, i = 32kk+8lq+e.
// ---------------------------------------------------------------------------
__global__ void pen_prep(const float* __restrict__ w1, const float* __restrict__ b1,
                         const float* __restrict__ w2,
                         unsigned short* __restrict__ w1t,
                         unsigned short* __restrict__ w2t)
{
    const int tid = threadIdx.x;
    for (int idx = tid; idx < 512; idx += 256) {
        const int cf = idx >> 6, lane = idx & 63;
        const int lq = lane >> 4, lr = lane & 15;
        const int chan = 32 * (cf >> 1) + 8 * (lr >> 2) + 4 * (cf & 1) + (lr & 3);
        #pragma unroll
        for (int e = 0; e < 8; ++e) {
            const int k = 8 * lq + e;
            float v = 0.f;
            if (k < 9)       v = w1[k * HH + chan];
            else if (k == 9) v = b1[chan];
            w1t[idx * 8 + e] = f2bf(v);
        }
    }
    for (int idx = tid; idx < 2048; idx += 256) {
        const int lane = idx & 63;
        const int fid  = idx >> 6;          // 0..31
        const int kk = fid & 3, of = (fid >> 2) & 1, w = fid >> 3;
        const int lq = lane >> 4, lr = lane & 15;
        const int o = w * 32 + of * 16 + lr;
        #pragma unroll
        for (int e = 0; e < 8; ++e) {
            const int i = 32 * kk + 8 * lq + e;
            w2t[idx * 8 + e] = f2bf(w2[i * HH + o]);
        }
    }
}

// ---------------------------------------------------------------------------
// Kernel A: block = (n, chunk of 1024 rows); 4 stages of 256 rows.
// Wave w: outputs [32w, 32w+32), iterates all 16 units (16 rows each) per stage.
// ---------------------------------------------------------------------------
__global__ __launch_bounds__(256, 4) void pen_inner(
    const float* __restrict__ x,
    const float* __restrict__ b2,
    const unsigned short* __restrict__ w1t,
    const unsigned short* __restrict__ w2t,
    float* __restrict__ partials)
{
    __shared__ __align__(16) unsigned short xw[XROW * RPS + 32];  // 12.4 KB

    const int tid  = threadIdx.x;
    const int wave = tid >> 6;
    const int lane = tid & 63;
    const int lr   = lane & 15;
    const int lq   = lane >> 4;

    const int bx    = blockIdx.x;
    const int n     = bx >> 2;
    const int chunk = bx & 3;

    const float* xn = x + n * (MM * TT);

    // ---- load fragment tables (coalesced b128 per lane) ----
    bf16x8 w1f[8];
    #pragma unroll
    for (int cf = 0; cf < 8; ++cf)
        w1f[cf] = *(const bf16x8*)&w1t[(cf * 64 + lane) * 8];
    bf16x8 w2f[2][4];
    #pragma unroll
    for (int of = 0; of < 2; ++of)
        #pragma unroll
        for (int kk = 0; kk < 4; ++kk)
            w2f[of][kk] = *(const bf16x8*)&w2t[(((wave * 2 + of) * 4 + kk) * 64 + lane) * 8];
    f32x4 b2f[2];
    #pragma unroll
    for (int of = 0; of < 2; ++of)
        #pragma unroll
        for (int j = 0; j < 4; ++j)
            b2f[of][j] = b2[wave * 32 + of * 16 + lq * 4 + j];

    if (tid < 32) xw[XROW * RPS + tid] = 0;   // pad row (lq=3 overread at r=255)

    const f32x4 zero4 = {0.f, 0.f, 0.f, 0.f};
    const int xo = XROW * lr + 8 * lq;        // per-lane xw read offset (hw)
    float colsum[2][4] = {{0,0,0,0},{0,0,0,0}};

    for (int st = 0; st < STAGES; ++st) {
        __syncthreads();   // prev stage's xw reads complete

        // ---- stage 256 window-rows as bf16; k=9 slot = 1.0 (bias channel) ----
        {
            const int r = tid;                 // RPS == blockDim
            const int rowg = chunk * 1024 + st * 256 + r;
            unsigned short kv[9];
            #pragma unroll
            for (int k = 0; k < 9; ++k) {      // k = i*3+m; coalesced over r per k
                const int i = k / 3;
                const int m = k - i * 3;
                const int t = rowg + i;
                kv[k] = (t < TT) ? f2bf(xn[m * TT + t]) : (unsigned short)0;
            }
            u16x4 s0, s1, s2;
            s0[0] = kv[0]; s0[1] = kv[1]; s0[2] = kv[2]; s0[3] = kv[3];
            s1[0] = kv[4]; s1[1] = kv[5]; s1[2] = kv[6]; s1[3] = kv[7];
            s2[0] = kv[8]; s2[1] = 0x3F80; s2[2] = 0; s2[3] = 0;   // 1.0 at k=9
            u16x4 z; z[0] = 0; z[1] = 0; z[2] = 0; z[3] = 0;
            *(u16x4*)&xw[XROW * r]      = s0;
            *(u16x4*)&xw[XROW * r + 4]  = s1;
            *(u16x4*)&xw[XROW * r + 8]  = s2;
            *(u16x4*)&xw[XROW * r + 12] = z;
            *(u16x4*)&xw[XROW * r + 16] = z;
            *(u16x4*)&xw[XROW * r + 20] = z;
        }
        __syncthreads();   // staging visible

        // ---- 16 independent 16-row units, every wave, no barriers ----
        #pragma unroll 2
        for (int u = 0; u < 16; ++u) {
            const bf16x8 bfrag = *(const bf16x8*)&xw[u * (XROW * 16) + xo];

            // interleaved L1 (permuted channels) -> relu+pack -> L2, per kk.
            // acc1 live range: one pair (8 VGPR); pa: one frag (4 VGPR).
            f32x4 acc2[2];
            #pragma unroll
            for (int kk = 0; kk < 4; ++kk) {
                f32x4 a0 = __builtin_amdgcn_mfma_f32_16x16x32_bf16(
                               w1f[2 * kk],     bfrag, zero4, 0, 0, 0);
                f32x4 a1 = __builtin_amdgcn_mfma_f32_16x16x32_bf16(
                               w1f[2 * kk + 1], bfrag, zero4, 0, 0, 0);
                u32x4 d;
                d[0] = (unsigned)f2bf(fmaxf(a0[0], 0.f))
                     | ((unsigned)f2bf(fmaxf(a0[1], 0.f)) << 16);
                d[1] = (unsigned)f2bf(fmaxf(a0[2], 0.f))
                     | ((unsigned)f2bf(fmaxf(a0[3], 0.f)) << 16);
                d[2] = (unsigned)f2bf(fmaxf(a1[0], 0.f))
                     | ((unsigned)f2bf(fmaxf(a1[1], 0.f)) << 16);
                d[3] = (unsigned)f2bf(fmaxf(a1[2], 0.f))
                     | ((unsigned)f2bf(fmaxf(a1[3], 0.f)) << 16);
                const bf16x8 pa = __builtin_bit_cast(bf16x8, d);
                if (kk == 0) {
                    acc2[0] = __builtin_amdgcn_mfma_f32_16x16x32_bf16(
                                  w2f[0][0], pa, b2f[0], 0, 0, 0);
                    acc2[1] = __builtin_amdgcn_mfma_f32_16x16x32_bf16(
                                  w2f[1][0], pa, b2f[1], 0, 0, 0);
                } else {
                    acc2[0] = __builtin_amdgcn_mfma_f32_16x16x32_bf16(
                                  w2f[0][kk], pa, acc2[0], 0, 0, 0);
                    acc2[1] = __builtin_amdgcn_mfma_f32_16x16x32_bf16(
                                  w2f[1][kk], pa, acc2[1], 0, 0, 0);
                }
            }

            // relu + column-sum (row index = lr); mask only the global tail
            if ((chunk == 3) && (st == 3) && (u == 15)) {
                const bool valid = lr < 14;        // rows 4080+lr < 4094
                #pragma unroll
                for (int of = 0; of < 2; ++of)
                    #pragma unroll
                    for (int j = 0; j < 4; ++j) {
                        float v = fmaxf(acc2[of][j], 0.f);
                        if (valid) colsum[of][j] += v;
                    }
            } else {
                #pragma unroll
                for (int of = 0; of < 2; ++of)
                    #pragma unroll
                    for (int j = 0; j < 4; ++j)
                        colsum[of][j] += fmaxf(acc2[of][j], 0.f);
            }
        }
    }

    // ---- reduce over the 16 row-lanes; each wave owns its 32 outputs ----
    #pragma unroll
    for (int of = 0; of < 2; ++of)
        #pragma unroll
        for (int j = 0; j < 4; ++j) {
            float v = colsum[of][j];
            #pragma unroll
            for (int msk = 1; msk < 16; msk <<= 1)
                v += __shfl_xor(v, msk, 64);
            if (lr == 0) {
                const int o = wave * 32 + of * 16 + lq * 4 + j;
                partials[(n * CHUNKS + chunk) * HH + o] = v;
            }
        }
}

// ---------------------------------------------------------------------------
// Kernel B: tail in fp32. inner = sum partials; oi = inner@W3 + L*b3;
// io = [x[:, :, :2] flat (6), oi]; g = relu(io@rw1+rb1); out = g@rw2+rb2.
// ---------------------------------------------------------------------------
__global__ __launch_bounds__(128) void pen_outer(
    const float* __restrict__ x,
    const float* __restrict__ w3, const float* __restrict__ b3,
    const float* __restrict__ rw1, const float* __restrict__ rb1,
    const float* __restrict__ rw2, const float* __restrict__ rb2,
    const float* __restrict__ partials,
    float* __restrict__ out)
{
    __shared__ float S[HH];
    __shared__ float IO[136];
    __shared__ float G[HH];
    const int n = blockIdx.x;
    const int c = threadIdx.x;

    float s = 0.f;
    #pragma unroll
    for (int ch = 0; ch < CHUNKS; ++ch)
        s += partials[(n * CHUNKS + ch) * HH + c];
    S[c] = s;
    if (c < 6) IO[c] = x[n * (MM * TT) + (c >> 1) * TT + (c & 1)];
    __syncthreads();

    float oi = (float)LL * b3[c];
    for (int k = 0; k < HH; ++k) oi += S[k] * w3[k * HH + c];
    IO[6 + c] = oi;
    __syncthreads();

    float g = rb1[c];
    for (int k = 0; k < 134; ++k) g += IO[k] * rw1[k * HH + c];
    G[c] = fmaxf(g, 0.f);
    __syncthreads();

    if (c < 10) {
        float o = rb2[c];
        for (int k = 0; k < HH; ++k) o += G[k] * rw2[k * 10 + c];
        out[n * 10 + c] = o;
    }
}

// ---------------------------------------------------------------------------
extern "C" void kernel_launch(void* const* d_in, const int* in_sizes, int n_in,
                              void* d_out, int out_size, void* d_ws, size_t ws_size,
                              hipStream_t stream)
{
    (void)in_sizes; (void)n_in; (void)out_size; (void)ws_size;
    const float* x   = (const float*)d_in[0];
    const float* w1  = (const float*)d_in[1];
    const float* b1  = (const float*)d_in[2];
    const float* w2  = (const float*)d_in[3];
    const float* b2  = (const float*)d_in[4];
    const float* w3  = (const float*)d_in[5];
    const float* b3  = (const float*)d_in[6];
    const float* rw1 = (const float*)d_in[7];
    const float* rb1 = (const float*)d_in[8];
    const float* rw2 = (const float*)d_in[9];
    const float* rb2 = (const float*)d_in[10];

    float*          partials = (float*)d_ws;                            // 512 KB
    unsigned short* w1t = (unsigned short*)((char*)d_ws + WS_W1);       // 8 KB
    unsigned short* w2t = (unsigned short*)((char*)d_ws + WS_W2);       // 32 KB

    pen_prep<<<1, 256, 0, stream>>>(w1, b1, w2, w1t, w2t);
    pen_inner<<<NN * CHUNKS, 256, 0, stream>>>(x, b2, w1t, w2t, partials);
    pen_outer<<<NN, 128, 0, stream>>>(x, w3, b3, rw1, rb1, rw2, rb2, partials,
                                      (float*)d_out);
}

// Round 9
// 78.344 us; speedup vs baseline: 1.4814x; 1.4814x over previous
//
#include <hip/hip_runtime.h>
#include <hip/hip_bf16.h>

// PartiallyExchangeableNetwork on MI355X (gfx950)
// N=256, M=3, T=4096, ORDER=2 -> L=4094 windows, H=128, OUT=10
//
// h1 = relu(xin @ W1 + b1); h2 = relu(h1 @ W2 + b2); colsum over L.
// Layer 3 folded through the sum: sum_l(h2@W3+b3) = (sum_l h2)@W3 + L*b3 (tail).
//
// R9 = R5 (best measured, 74us) + two fixes:
//  - h1s double-buffered: 1 barrier/step (+1/half) instead of 2/step.
//  - bf16 packing via v_cvt_pk_bf16_f32 (__float22bfloat162_rn), both for the
//    h1 pack and the xw staging.

#define NN 256
#define MM 3
#define TT 4096
#define LL 4094
#define HH 128
#define CHUNKS 8
#define RPC 512          // rows (windows) per chunk (2 halves of 256)
#define RPH 256          // rows per staged half
#define HALVES 2
#define STEPS 4          // 64-row steps per half
#define SR 64            // rows per step (block tile)
#define XROW 24          // xw row stride in halfwords (48 B)

typedef __attribute__((ext_vector_type(8))) short bf16x8;
typedef __attribute__((ext_vector_type(4))) float f32x4;
typedef __attribute__((ext_vector_type(4))) unsigned short u16x4;
typedef __attribute__((ext_vector_type(2))) unsigned int u32x2;

__device__ __forceinline__ unsigned short f2bf(float x) {
    __hip_bfloat16 h = __float2bfloat16(x);           // RNE, hw cvt on gfx950
    union { __hip_bfloat16 h; unsigned short u; } v; v.h = h;
    return v.u;
}

// packed pair: low16 = bf16(a), high16 = bf16(b) -- compiles to v_cvt_pk_bf16_f32
__device__ __forceinline__ unsigned pkbf2(float a, float b) {
    union { __hip_bfloat162 h; unsigned u; } v;
    v.h = __float22bfloat162_rn(make_float2(a, b));
    return v.u;
}

// ---------------------------------------------------------------------------
// Kernel A: per (n, chunk-of-512-windows): layers 1+2, masked column sums.
// Wave w owns output channels [32w, 32w+32); all 64 rows of each step.
//
// xw layout: row r at halfwords [24r, 24r+24): k0..8 data, k9..23 zero.
// L1 B-fragment read: one 16B-aligned ds_read_b128 per lane; lq>=2 lanes read
// zero pad / next-row data multiplied by zeroed A columns k>=9.
// ---------------------------------------------------------------------------
__global__ __launch_bounds__(256, 4) void pen_inner(
    const float* __restrict__ x,
    const float* __restrict__ w1, const float* __restrict__ b1,
    const float* __restrict__ w2, const float* __restrict__ b2,
    float* __restrict__ partials)
{
    __shared__ __align__(16) unsigned short xw[XROW * (RPH + 1) + 8]; // 12.4 KB
    __shared__ __align__(16) unsigned short h1s[2][SR * HH];          // 32.8 KB

    const int tid  = threadIdx.x;
    const int wave = tid >> 6;
    const int lane = tid & 63;
    const int lr   = lane & 15;   // MFMA "lane&15" index (A-row / B-col / D-col)
    const int lq   = lane >> 4;   // 0..3

    const int bx    = blockIdx.x;
    const int n     = bx >> 3;
    const int chunk = bx & 7;
    const int l0c   = chunk * RPC;

    const float* xn = x + n * (MM * TT);

    // ---- preload weight fragments; biases go into the MFMA C operand ----
    const int fo0 = wave * 2;              // this wave's two 16-wide o-fragments
    bf16x8 w1f[2];                         // A1 = W1^T : [c][k], k>=9 zeroed
    bf16x8 w2f[2][4];                      // A2 = W2^T : [o][i], 4 k-chunks of 32
    f32x4  b1f[2], b2f[2];                 // bias in D-layout (row = lq*4+j)
    #pragma unroll
    for (int f = 0; f < 2; ++f) {
        const int c = (fo0 + f) * 16 + lr;
        bf16x8 a;
        #pragma unroll
        for (int e = 0; e < 8; ++e) {
            int k = lq * 8 + e;
            a[e] = (short)((k < 9) ? f2bf(w1[k * HH + c]) : (unsigned short)0);
        }
        w1f[f] = a;
        #pragma unroll
        for (int kk = 0; kk < 4; ++kk) {
            bf16x8 wv;
            #pragma unroll
            for (int e = 0; e < 8; ++e)
                wv[e] = (short)f2bf(w2[(kk * 32 + lq * 8 + e) * HH + c]);
            w2f[f][kk] = wv;
        }
        #pragma unroll
        for (int j = 0; j < 4; ++j) {
            b1f[f][j] = b1[(fo0 + f) * 16 + lq * 4 + j];
            b2f[f][j] = b2[(fo0 + f) * 16 + lq * 4 + j];
        }
    }

    // zero the tail row (row 256, read by lq=3 overread at r=255) once
    if (tid < XROW + 8) xw[XROW * RPH + tid] = 0;

    // per-lane xw read offset (halfwords)
    const int xo = XROW * lr + 8 * lq;

    float colsum[2][4] = {{0.f,0.f,0.f,0.f},{0.f,0.f,0.f,0.f}};

    for (int half = 0; half < HALVES; ++half) {
        const int lbase = l0c + half * RPH;

        // ---- stage this half's 256 window-rows as bf16 ----
        // Safe: every wave's xw reads for the previous half happen before that
        // half's last post-h1-write barrier, which all threads have passed.
        {
            const int r = tid;             // RPH == blockDim
            float kv[9];
            #pragma unroll
            for (int k = 0; k < 9; ++k) {  // k = i*3+m; coalesced over r per k
                const int i = k / 3;
                const int m = k - i * 3;
                const int t = lbase + r + i;
                kv[k] = (t < TT) ? xn[m * TT + t] : 0.f;
            }
            u32x2 p0, p1, p2, z2;
            p0[0] = pkbf2(kv[0], kv[1]); p0[1] = pkbf2(kv[2], kv[3]);
            p1[0] = pkbf2(kv[4], kv[5]); p1[1] = pkbf2(kv[6], kv[7]);
            p2[0] = pkbf2(kv[8], 0.f);   p2[1] = 0u;
            z2[0] = 0u; z2[1] = 0u;
            *(u32x2*)&xw[XROW * r]      = p0;
            *(u32x2*)&xw[XROW * r + 4]  = p1;
            *(u32x2*)&xw[XROW * r + 8]  = p2;
            *(u32x2*)&xw[XROW * r + 12] = z2;
            *(u32x2*)&xw[XROW * r + 16] = z2;
            *(u32x2*)&xw[XROW * r + 20] = z2;
        }
        __syncthreads();   // staging visible before first L1 reads of this half

        for (int s = 0; s < STEPS; ++s) {
            const int buf = (half * STEPS + s) & 1;
            unsigned short* hb = &h1s[buf][0];

            // ---- layer 1: D1[c][r] = W1^T @ xin^T + b1 (bias via C operand) ----
            f32x4 acc1[2][4];
            #pragma unroll
            for (int rf = 0; rf < 4; ++rf) {
                bf16x8 bfrag = *(const bf16x8*)&xw[s * (XROW * SR) + rf * (XROW * 16) + xo];
                acc1[0][rf] = __builtin_amdgcn_mfma_f32_16x16x32_bf16(w1f[0], bfrag, b1f[0], 0, 0, 0);
                acc1[1][rf] = __builtin_amdgcn_mfma_f32_16x16x32_bf16(w1f[1], bfrag, b1f[1], 0, 0, 0);
            }

            // ---- relu + cvt_pk + swizzled LDS store: h1s[r][c], idx ^= (r&7)<<3 ----
            #pragma unroll
            for (int rf = 0; rf < 4; ++rf) {
                const int r   = rf * 16 + lr;
                const int swz = (r & 7) << 3;
                #pragma unroll
                for (int f = 0; f < 2; ++f) {
                    const int cb = (fo0 + f) * 16 + lq * 4;
                    u32x2 pk;
                    pk[0] = pkbf2(fmaxf(acc1[f][rf][0], 0.f), fmaxf(acc1[f][rf][1], 0.f));
                    pk[1] = pkbf2(fmaxf(acc1[f][rf][2], 0.f), fmaxf(acc1[f][rf][3], 0.f));
                    *(u32x2*)&h1s[buf][r * HH + (cb ^ swz)] = pk;
                }
            }
            __syncthreads();   // h1 tile ready (dbuf removes the WAR barrier)

            // ---- layer 2: D2[o][r] = W2^T @ h1^T + b2, 4 K-chunks ----
            f32x4 acc2[2][4];
            #pragma unroll
            for (int rf = 0; rf < 4; ++rf) {
                const int r   = rf * 16 + lr;
                const int swz = (r & 7) << 3;
                bf16x8 hf[4];
                #pragma unroll
                for (int kk = 0; kk < 4; ++kk)
                    hf[kk] = *(const bf16x8*)&hb[r * HH + ((kk * 32 + lq * 8) ^ swz)];
                acc2[0][rf] = __builtin_amdgcn_mfma_f32_16x16x32_bf16(w2f[0][0], hf[0], b2f[0], 0, 0, 0);
                acc2[1][rf] = __builtin_amdgcn_mfma_f32_16x16x32_bf16(w2f[1][0], hf[0], b2f[1], 0, 0, 0);
                #pragma unroll
                for (int kk = 1; kk < 4; ++kk) {
                    acc2[0][rf] = __builtin_amdgcn_mfma_f32_16x16x32_bf16(w2f[0][kk], hf[kk], acc2[0][rf], 0, 0, 0);
                    acc2[1][rf] = __builtin_amdgcn_mfma_f32_16x16x32_bf16(w2f[1][kk], hf[kk], acc2[1][rf], 0, 0, 0);
                }
            }

            // ---- relu + column-sum; tail mask only on the one affected rf ----
            const bool tailstep = (chunk == CHUNKS - 1) && (half == HALVES - 1)
                                  && (s == STEPS - 1);
            #pragma unroll
            for (int rf = 0; rf < 4; ++rf) {
                if (tailstep && rf == 3) {              // rows 4080+lr; valid iff lr<14
                    const bool valid = lr < 14;
                    #pragma unroll
                    for (int f = 0; f < 2; ++f)
                        #pragma unroll
                        for (int j = 0; j < 4; ++j) {
                            float v = fmaxf(acc2[f][rf][j], 0.f);
                            if (valid) colsum[f][j] += v;
                        }
                } else {
                    #pragma unroll
                    for (int f = 0; f < 2; ++f)
                        #pragma unroll
                        for (int j = 0; j < 4; ++j)
                            colsum[f][j] += fmaxf(acc2[f][rf][j], 0.f);
                }
            }
        }
    }

    // ---- reduce colsum over the 16 r-lanes, write block partial (no atomics) ----
    #pragma unroll
    for (int f = 0; f < 2; ++f)
        #pragma unroll
        for (int j = 0; j < 4; ++j) {
            float v = colsum[f][j];
            #pragma unroll
            for (int msk = 1; msk < 16; msk <<= 1)
                v += __shfl_xor(v, msk, 64);
            if (lr == 0) {
                const int o = (fo0 + f) * 16 + lq * 4 + j;
                partials[(n * CHUNKS + chunk) * HH + o] = v;
            }
        }
}

// ---------------------------------------------------------------------------
// Kernel B: tail in fp32. inner = sum partials; oi = inner@W3 + L*b3;
// io = [x[:, :, :2] flat (6), oi]; g = relu(io@rw1+rb1); out = g@rw2+rb2.
// ---------------------------------------------------------------------------
__global__ __launch_bounds__(128) void pen_outer(
    const float* __restrict__ x,
    const float* __restrict__ w3, const float* __restrict__ b3,
    const float* __restrict__ rw1, const float* __restrict__ rb1,
    const float* __restrict__ rw2, const float* __restrict__ rb2,
    const float* __restrict__ partials,
    float* __restrict__ out)
{
    __shared__ float S[HH];
    __shared__ float IO[136];
    __shared__ float G[HH];
    const int n = blockIdx.x;
    const int c = threadIdx.x;

    float s = 0.f;
    #pragma unroll
    for (int ch = 0; ch < CHUNKS; ++ch)
        s += partials[(n * CHUNKS + ch) * HH + c];
    S[c] = s;
    if (c < 6) IO[c] = x[n * (MM * TT) + (c >> 1) * TT + (c & 1)];
    __syncthreads();

    float oi = (float)LL * b3[c];
    for (int k = 0; k < HH; ++k) oi += S[k] * w3[k * HH + c];
    IO[6 + c] = oi;
    __syncthreads();

    float g = rb1[c];
    for (int k = 0; k < 134; ++k) g += IO[k] * rw1[k * HH + c];
    G[c] = fmaxf(g, 0.f);
    __syncthreads();

    if (c < 10) {
        float o = rb2[c];
        for (int k = 0; k < HH; ++k) o += G[k] * rw2[k * 10 + c];
        out[n * 10 + c] = o;
    }
}

// ---------------------------------------------------------------------------
extern "C" void kernel_launch(void* const* d_in, const int* in_sizes, int n_in,
                              void* d_out, int out_size, void* d_ws, size_t ws_size,
                              hipStream_t stream)
{
    (void)in_sizes; (void)n_in; (void)out_size; (void)ws_size;
    const float* x   = (const float*)d_in[0];
    const float* w1  = (const float*)d_in[1];
    const float* b1  = (const float*)d_in[2];
    const float* w2  = (const float*)d_in[3];
    const float* b2  = (const float*)d_in[4];
    const float* w3  = (const float*)d_in[5];
    const float* b3  = (const float*)d_in[6];
    const float* rw1 = (const float*)d_in[7];
    const float* rb1 = (const float*)d_in[8];
    const float* rw2 = (const float*)d_in[9];
    const float* rb2 = (const float*)d_in[10];

    float* partials = (float*)d_ws;   // NN*CHUNKS*HH floats = 1 MiB of scratch

    pen_inner<<<NN * CHUNKS, 256, 0, stream>>>(x, w1, b1, w2, b2, partials);
    pen_outer<<<NN, 128, 0, stream>>>(x, w3, b3, rw1, rb1, rw2, rb2, partials,
                                      (float*)d_out);
}